// Round 2
// baseline (1953.361 us; speedup 1.0000x reference)
//
#include <hip/hip_runtime.h>
#include <cstddef>

// Decoder tree-GRU, MI355X gfx950.
// B=32768, I=H=128, O=32, DEPTH=5, ARITY=2 -> 63 preorder nodes.
// Strategy: host-unrolled preorder launch sequence; bf16 MFMA 16x16x32 GEMMs
// with f32 accumulation; fused GRU-combine + child-pred epilogues.

#define BATCH 32768
#define TDEPTH 5
#define NBLK (BATCH / 64)

typedef float f32x4 __attribute__((ext_vector_type(4)));
typedef short s16x8 __attribute__((ext_vector_type(8)));
typedef unsigned short u16;

__device__ __forceinline__ float bf2f(u16 u) {
  unsigned x = ((unsigned)u) << 16;
  return __builtin_bit_cast(float, x);
}
__device__ __forceinline__ u16 f2bf(float f) {
  unsigned u = __builtin_bit_cast(unsigned, f);
  u += 0x7fffu + ((u >> 16) & 1u);
  return (u16)(u >> 16);
}
__device__ __forceinline__ float sigm(float x) { return 1.f / (1.f + __expf(-x)); }
__device__ __forceinline__ float tanhfast(float x) { return 1.f - 2.f / (__expf(2.f * x) + 1.f); }
__device__ __forceinline__ f32x4 mf(s16x8 a, s16x8 b, f32x4 c) {
  return __builtin_amdgcn_mfma_f32_16x16x32_bf16(a, b, c, 0, 0, 0);
}

// ---------------- prep: pack all weights transposed [N][K] bf16 ----------------
// Wz   [128][128]  : z2h_w^T
// Wo   [ 32][128]  : h2o_w^T
// Wcat [512][160]  : rows 0-255 gate r,z: k<32 -> wi[g], k>=32 -> wh[g]
//                    rows 256-383 (gi_n): k<32 -> wi[2], else 0
//                    rows 384-511 (gh_n): k<32 -> 0, else wh[2]
// Wu   [128][256]  : k<128 -> uf_w^T, k>=128 -> ua_w^T
__global__ void prep_kernel(const float* __restrict__ z2h_w, const float* __restrict__ h2o_w,
                            const float* __restrict__ anc_wi, const float* __restrict__ anc_wh,
                            const float* __restrict__ frat_wi, const float* __restrict__ frat_wh,
                            const float* __restrict__ ua_w, const float* __restrict__ uf_w,
                            u16* __restrict__ Wz, u16* __restrict__ Wo, u16* __restrict__ Wanc,
                            u16* __restrict__ Wfrat, u16* __restrict__ Wu) {
  int tid = blockIdx.x * blockDim.x + threadIdx.x;
  int stride = gridDim.x * blockDim.x;
  for (int i = tid; i < 128 * 128; i += stride) {
    int n = i / 128, k = i % 128;
    Wz[n * 128 + k] = f2bf(z2h_w[k * 128 + n]);
  }
  for (int i = tid; i < 32 * 128; i += stride) {
    int n = i / 128, k = i % 128;
    Wo[n * 128 + k] = f2bf(h2o_w[k * 32 + n]);
  }
  for (int i = tid; i < 512 * 160; i += stride) {
    int n = i / 160, k = i % 160;
    float va, vf;
    if (n < 256) {
      int g = n >> 7, hc = n & 127;
      if (k < 32) { va = anc_wi[g * 32 * 128 + k * 128 + hc]; vf = frat_wi[g * 32 * 128 + k * 128 + hc]; }
      else        { va = anc_wh[g * 128 * 128 + (k - 32) * 128 + hc]; vf = frat_wh[g * 128 * 128 + (k - 32) * 128 + hc]; }
    } else if (n < 384) {
      int hc = n - 256;
      if (k < 32) { va = anc_wi[2 * 32 * 128 + k * 128 + hc]; vf = frat_wi[2 * 32 * 128 + k * 128 + hc]; }
      else        { va = 0.f; vf = 0.f; }
    } else {
      int hc = n - 384;
      if (k < 32) { va = 0.f; vf = 0.f; }
      else        { va = anc_wh[2 * 128 * 128 + (k - 32) * 128 + hc]; vf = frat_wh[2 * 128 * 128 + (k - 32) * 128 + hc]; }
    }
    Wanc[i] = f2bf(va);
    Wfrat[i] = f2bf(vf);
  }
  for (int i = tid; i < 128 * 256; i += stride) {
    int n = i / 256, k = i % 256;
    float v = (k < 128) ? uf_w[k * 128 + n] : ua_w[(k - 128) * 128 + n];
    Wu[i] = f2bf(v);
  }
}

// per-row softmax of 32 f32 -> bf16 into LDS row (called by 64 threads)
__device__ __forceinline__ void softmax32_to_lds(const float* __restrict__ p, u16* dst) {
  float v[32];
  const float4* p4 = (const float4*)p;
#pragma unroll
  for (int i = 0; i < 8; i++) {
    float4 q = p4[i];
    v[4 * i] = q.x; v[4 * i + 1] = q.y; v[4 * i + 2] = q.z; v[4 * i + 3] = q.w;
  }
  float mx = -1e30f;
#pragma unroll
  for (int i = 0; i < 32; i++) mx = fmaxf(mx, v[i]);
  float s = 0.f;
#pragma unroll
  for (int i = 0; i < 32; i++) { v[i] = __expf(v[i] - mx); s += v[i]; }
  float inv = 1.f / s;
#pragma unroll
  for (int i = 0; i < 32; i++) dst[i] = f2bf(v[i] * inv);
}

// ---------------- init: hidden0 = z @ z2h_w + b ; pred0 = hidden0 @ h2o + b ----
__global__ __launch_bounds__(512) void init_kernel(
    const float* __restrict__ z, const u16* __restrict__ Wz, const float* __restrict__ z2h_b,
    const u16* __restrict__ Wo, const float* __restrict__ h2o_b,
    u16* __restrict__ h_out, float* __restrict__ pred_out) {
  __shared__ u16 A1[64 * 136];
  __shared__ u16 H2[64 * 136];
  const int tid = threadIdx.x;
  const int brow = blockIdx.x * 64;
  for (int c = tid; c < 64 * 32; c += 512) {  // 64 rows x 128 f32, 4-f32 chunks
    int r = c >> 5, cc = (c & 31) * 4;
    const float4 v = *(const float4*)(z + (size_t)(brow + r) * 128 + cc);
    u16* dst = &A1[r * 136 + cc];
    dst[0] = f2bf(v.x); dst[1] = f2bf(v.y); dst[2] = f2bf(v.z); dst[3] = f2bf(v.w);
  }
  __syncthreads();
  const int w = tid >> 6, l = tid & 63;
  const int r2 = w >> 2, cg = w & 3, lr = l & 15, lk = (l >> 4) * 8;
  f32x4 acc[2][2] = {};
#pragma unroll
  for (int ks = 0; ks < 4; ++ks) {
    s16x8 a[2];
#pragma unroll
    for (int mt = 0; mt < 2; ++mt)
      a[mt] = *(const s16x8*)&A1[(32 * r2 + 16 * mt + lr) * 136 + ks * 32 + lk];
#pragma unroll
    for (int nt = 0; nt < 2; ++nt) {
      int n = 32 * cg + 16 * nt + lr;
      s16x8 b = *(const s16x8*)&Wz[n * 128 + ks * 32 + lk];
#pragma unroll
      for (int mt = 0; mt < 2; ++mt) acc[mt][nt] = mf(a[mt], b, acc[mt][nt]);
    }
  }
#pragma unroll
  for (int mt = 0; mt < 2; ++mt)
#pragma unroll
    for (int nt = 0; nt < 2; ++nt) {
      int hc = 32 * cg + 16 * nt + lr;
      float bias = z2h_b[hc];
#pragma unroll
      for (int r = 0; r < 4; ++r) {
        int row = 32 * r2 + 16 * mt + (l >> 4) * 4 + r;
        u16 bv = f2bf(acc[mt][nt][r] + bias);
        h_out[(size_t)(brow + row) * 128 + hc] = bv;
        H2[row * 136 + hc] = bv;
      }
    }
  __syncthreads();
  {
    const int m4 = w >> 1, n2 = w & 1;
    f32x4 pacc = {};
#pragma unroll
    for (int ks = 0; ks < 4; ++ks) {
      s16x8 a = *(const s16x8*)&H2[(16 * m4 + lr) * 136 + ks * 32 + lk];
      s16x8 b = *(const s16x8*)&Wo[(16 * n2 + lr) * 128 + ks * 32 + lk];
      pacc = mf(a, b, pacc);
    }
    int o = 16 * n2 + lr;
    float bias = h2o_b[o];
#pragma unroll
    for (int r = 0; r < 4; ++r) {
      int row = 16 * m4 + (l >> 4) * 4 + r;
      pred_out[(size_t)(brow + row) * 32 + o] = pacc[r] + bias;
    }
  }
}

// ------------- anc GRU: h_ai = GRU(softmax(pred), h) ; child pred --------------
__global__ __launch_bounds__(512) void anc_kernel(
    const u16* __restrict__ h_in, const float* __restrict__ pred_in,
    const u16* __restrict__ Wcat, const float* __restrict__ bi, const float* __restrict__ bh,
    const u16* __restrict__ Wo, const float* __restrict__ h2o_b,
    u16* __restrict__ h_out, float* __restrict__ pred_out) {
  __shared__ u16 A1[64 * 168];  // [probs(32) | h(128)] + pad
  __shared__ u16 H2[64 * 136];
  const int tid = threadIdx.x;
  const int brow = blockIdx.x * 64;
  for (int c = tid; c < 64 * 16; c += 512) {
    int r = c >> 4, cc = (c & 15) * 8;
    *(s16x8*)&A1[r * 168 + 32 + cc] = *(const s16x8*)(h_in + (size_t)(brow + r) * 128 + cc);
  }
  if (tid < 64) softmax32_to_lds(pred_in + (size_t)(brow + tid) * 32, &A1[tid * 168]);
  __syncthreads();
  const int w = tid >> 6, l = tid & 63;
  const int r2 = w >> 2, cg = w & 3, lr = l & 15, lk = (l >> 4) * 8;
  f32x4 acc[4][2][2] = {};
#pragma unroll
  for (int ks = 0; ks < 5; ++ks) {
    s16x8 a[2];
#pragma unroll
    for (int mt = 0; mt < 2; ++mt)
      a[mt] = *(const s16x8*)&A1[(32 * r2 + 16 * mt + lr) * 168 + ks * 32 + lk];
#pragma unroll
    for (int gb = 0; gb < 4; ++gb) {
      if (gb == 2 && ks > 0) continue;  // gi_n block: only k<32 is nonzero
#pragma unroll
      for (int nt = 0; nt < 2; ++nt) {
        int n = 128 * gb + 32 * cg + 16 * nt + lr;
        s16x8 b = *(const s16x8*)&Wcat[(size_t)n * 160 + ks * 32 + lk];
#pragma unroll
        for (int mt = 0; mt < 2; ++mt) acc[gb][mt][nt] = mf(a[mt], b, acc[gb][mt][nt]);
      }
    }
  }
#pragma unroll
  for (int mt = 0; mt < 2; ++mt)
#pragma unroll
    for (int nt = 0; nt < 2; ++nt) {
      int hc = 32 * cg + 16 * nt + lr;
      float b0 = bi[hc] + bh[hc];
      float b1 = bi[128 + hc] + bh[128 + hc];
      float b2i = bi[256 + hc], b2h = bh[256 + hc];
#pragma unroll
      for (int r = 0; r < 4; ++r) {
        int row = 32 * r2 + 16 * mt + (l >> 4) * 4 + r;
        float rr = sigm(acc[0][mt][nt][r] + b0);
        float zz = sigm(acc[1][mt][nt][r] + b1);
        float nn = tanhfast(acc[2][mt][nt][r] + b2i + rr * (acc[3][mt][nt][r] + b2h));
        float hold = bf2f(A1[row * 168 + 32 + hc]);
        float hv = (1.f - zz) * nn + zz * hold;
        u16 bv = f2bf(hv);
        h_out[(size_t)(brow + row) * 128 + hc] = bv;
        H2[row * 136 + hc] = bv;
      }
    }
  __syncthreads();
  {
    const int m4 = w >> 1, n2 = w & 1;
    f32x4 pacc = {};
#pragma unroll
    for (int ks = 0; ks < 4; ++ks) {
      s16x8 a = *(const s16x8*)&H2[(16 * m4 + lr) * 136 + ks * 32 + lk];
      s16x8 b = *(const s16x8*)&Wo[(16 * n2 + lr) * 128 + ks * 32 + lk];
      pacc = mf(a, b, pacc);
    }
    int o = 16 * n2 + lr;
    float bias = h2o_b[o];
#pragma unroll
    for (int r = 0; r < 4; ++r) {
      int row = 16 * m4 + (l >> 4) * 4 + r;
      pred_out[(size_t)(brow + row) * 32 + o] = pacc[r] + bias;
    }
  }
}

// --- frat: hf=GRU(softmax(pred_f),h_ai); h2=tanh(hf@uf+h_anc@ua+b); child pred --
__global__ __launch_bounds__(512) void frat_kernel(
    const float* __restrict__ predf_in, const u16* __restrict__ hai_in,
    const u16* __restrict__ hanc_in,
    const u16* __restrict__ Wcat, const float* __restrict__ bi, const float* __restrict__ bh,
    const u16* __restrict__ Wu, const float* __restrict__ uf_b, const float* __restrict__ ua_b,
    const u16* __restrict__ Wo, const float* __restrict__ h2o_b,
    u16* __restrict__ h_out, float* __restrict__ pred_out) {
  __shared__ u16 A1[64 * 168];  // [probs_f(32) | h_ai(128)]
  __shared__ u16 A2[64 * 264];  // [hf_new(128) | h_anc(128)]
  __shared__ u16 H2[64 * 136];
  const int tid = threadIdx.x;
  const int brow = blockIdx.x * 64;
  for (int c = tid; c < 64 * 16; c += 512) {
    int r = c >> 4, cc = (c & 15) * 8;
    *(s16x8*)&A1[r * 168 + 32 + cc] = *(const s16x8*)(hai_in + (size_t)(brow + r) * 128 + cc);
    *(s16x8*)&A2[r * 264 + 128 + cc] = *(const s16x8*)(hanc_in + (size_t)(brow + r) * 128 + cc);
  }
  if (tid < 64) softmax32_to_lds(predf_in + (size_t)(brow + tid) * 32, &A1[tid * 168]);
  __syncthreads();
  const int w = tid >> 6, l = tid & 63;
  const int r2 = w >> 2, cg = w & 3, lr = l & 15, lk = (l >> 4) * 8;
  {
    f32x4 acc[4][2][2] = {};
#pragma unroll
    for (int ks = 0; ks < 5; ++ks) {
      s16x8 a[2];
#pragma unroll
      for (int mt = 0; mt < 2; ++mt)
        a[mt] = *(const s16x8*)&A1[(32 * r2 + 16 * mt + lr) * 168 + ks * 32 + lk];
#pragma unroll
      for (int gb = 0; gb < 4; ++gb) {
        if (gb == 2 && ks > 0) continue;
#pragma unroll
        for (int nt = 0; nt < 2; ++nt) {
          int n = 128 * gb + 32 * cg + 16 * nt + lr;
          s16x8 b = *(const s16x8*)&Wcat[(size_t)n * 160 + ks * 32 + lk];
#pragma unroll
          for (int mt = 0; mt < 2; ++mt) acc[gb][mt][nt] = mf(a[mt], b, acc[gb][mt][nt]);
        }
      }
    }
#pragma unroll
    for (int mt = 0; mt < 2; ++mt)
#pragma unroll
      for (int nt = 0; nt < 2; ++nt) {
        int hc = 32 * cg + 16 * nt + lr;
        float b0 = bi[hc] + bh[hc];
        float b1 = bi[128 + hc] + bh[128 + hc];
        float b2i = bi[256 + hc], b2h = bh[256 + hc];
#pragma unroll
        for (int r = 0; r < 4; ++r) {
          int row = 32 * r2 + 16 * mt + (l >> 4) * 4 + r;
          float rr = sigm(acc[0][mt][nt][r] + b0);
          float zz = sigm(acc[1][mt][nt][r] + b1);
          float nn = tanhfast(acc[2][mt][nt][r] + b2i + rr * (acc[3][mt][nt][r] + b2h));
          float hold = bf2f(A1[row * 168 + 32 + hc]);
          float hfv = (1.f - zz) * nn + zz * hold;
          A2[row * 264 + hc] = f2bf(hfv);  // hf_new only feeds the uf matmul
        }
      }
  }
  __syncthreads();
  {
    f32x4 acc2[2][2] = {};
#pragma unroll
    for (int ks = 0; ks < 8; ++ks) {
      s16x8 a[2];
#pragma unroll
      for (int mt = 0; mt < 2; ++mt)
        a[mt] = *(const s16x8*)&A2[(32 * r2 + 16 * mt + lr) * 264 + ks * 32 + lk];
#pragma unroll
      for (int nt = 0; nt < 2; ++nt) {
        int n = 32 * cg + 16 * nt + lr;
        s16x8 b = *(const s16x8*)&Wu[(size_t)n * 256 + ks * 32 + lk];
#pragma unroll
        for (int mt = 0; mt < 2; ++mt) acc2[mt][nt] = mf(a[mt], b, acc2[mt][nt]);
      }
    }
#pragma unroll
    for (int mt = 0; mt < 2; ++mt)
#pragma unroll
      for (int nt = 0; nt < 2; ++nt) {
        int hc = 32 * cg + 16 * nt + lr;
        float bias = uf_b[hc] + ua_b[hc];
#pragma unroll
        for (int r = 0; r < 4; ++r) {
          int row = 32 * r2 + 16 * mt + (l >> 4) * 4 + r;
          u16 bv = f2bf(tanhfast(acc2[mt][nt][r] + bias));
          h_out[(size_t)(brow + row) * 128 + hc] = bv;
          H2[row * 136 + hc] = bv;
        }
      }
  }
  __syncthreads();
  {
    const int m4 = w >> 1, n2 = w & 1;
    f32x4 pacc = {};
#pragma unroll
    for (int ks = 0; ks < 4; ++ks) {
      s16x8 a = *(const s16x8*)&H2[(16 * m4 + lr) * 136 + ks * 32 + lk];
      s16x8 b = *(const s16x8*)&Wo[(16 * n2 + lr) * 128 + ks * 32 + lk];
      pacc = mf(a, b, pacc);
    }
    int o = 16 * n2 + lr;
    float bias = h2o_b[o];
#pragma unroll
    for (int r = 0; r < 4; ++r) {
      int row = 16 * m4 + (l >> 4) * 4 + r;
      pred_out[(size_t)(brow + row) * 32 + o] = pacc[r] + bias;
    }
  }
}

// ---------------------------------- host -------------------------------------
struct RecCtx {
  hipStream_t stream;
  float* out;
  u16 *Wanc, *Wfrat, *Wu, *Wo;
  const float *anc_bi, *anc_bh, *frat_bi, *frat_bh, *uf_b, *ua_b, *h2o_b;
  u16* Hlev[6];   // H[0..5] (second-child hiddens per level; [5] = root)
  u16* HAlev[6];  // HA[1..5] (first-child hiddens per level)

  void go(u16* h, int d, int idx) {
    if (d == 0) return;
    const size_t PB = (size_t)BATCH * 32;
    u16* hai = HAlev[d];
    hipLaunchKernelGGL(anc_kernel, dim3(NBLK), dim3(512), 0, stream,
                       h, out + (size_t)idx * PB, Wanc, anc_bi, anc_bh, Wo, h2o_b,
                       hai, out + (size_t)(idx + 1) * PB);
    go(hai, d - 1, idx + 1);
    int c2 = idx + (1 << d);  // idx + 1 + (2^d - 1)
    u16* hn = Hlev[d - 1];
    hipLaunchKernelGGL(frat_kernel, dim3(NBLK), dim3(512), 0, stream,
                       out + (size_t)(idx + 1) * PB, hai, h, Wfrat, frat_bi, frat_bh,
                       Wu, uf_b, ua_b, Wo, h2o_b, hn, out + (size_t)c2 * PB);
    go(hn, d - 1, c2);
  }
};

extern "C" void kernel_launch(void* const* d_in, const int* in_sizes, int n_in,
                              void* d_out, int out_size, void* d_ws, size_t ws_size,
                              hipStream_t stream) {
  const float* z       = (const float*)d_in[0];
  const float* z2h_w   = (const float*)d_in[1];
  const float* z2h_b   = (const float*)d_in[2];
  const float* h2o_w   = (const float*)d_in[3];
  const float* h2o_b   = (const float*)d_in[4];
  const float* anc_wi  = (const float*)d_in[5];
  const float* anc_wh  = (const float*)d_in[6];
  const float* anc_bi  = (const float*)d_in[7];
  const float* anc_bh  = (const float*)d_in[8];
  const float* frat_wi = (const float*)d_in[9];
  const float* frat_wh = (const float*)d_in[10];
  const float* frat_bi = (const float*)d_in[11];
  const float* frat_bh = (const float*)d_in[12];
  const float* ua_w    = (const float*)d_in[13];
  const float* ua_b    = (const float*)d_in[14];
  const float* uf_w    = (const float*)d_in[15];
  const float* uf_b    = (const float*)d_in[16];
  // depth (d_in[17]) and arity (d_in[18]) are compile-time constants here.

  u16* Wz    = (u16*)d_ws;
  u16* Wo    = Wz + 128 * 128;
  u16* Wanc  = Wo + 32 * 128;
  u16* Wfrat = Wanc + 512 * 160;
  u16* Wu    = Wfrat + 512 * 160;
  u16* Hbase = (u16*)((char*)d_ws + 512 * 1024);
  float* out = (float*)d_out;

  hipLaunchKernelGGL(prep_kernel, dim3(128), dim3(256), 0, stream,
                     z2h_w, h2o_w, anc_wi, anc_wh, frat_wi, frat_wh, ua_w, uf_w,
                     Wz, Wo, Wanc, Wfrat, Wu);

  RecCtx R;
  R.stream = stream; R.out = out;
  R.Wanc = Wanc; R.Wfrat = Wfrat; R.Wu = Wu; R.Wo = Wo;
  R.anc_bi = anc_bi; R.anc_bh = anc_bh; R.frat_bi = frat_bi; R.frat_bh = frat_bh;
  R.uf_b = uf_b; R.ua_b = ua_b; R.h2o_b = h2o_b;
  for (int i = 0; i < 6; i++) R.Hlev[i] = Hbase + (size_t)i * ((size_t)BATCH * 128);
  for (int d = 1; d <= 5; d++) R.HAlev[d] = Hbase + (size_t)(5 + d) * ((size_t)BATCH * 128);

  hipLaunchKernelGGL(init_kernel, dim3(NBLK), dim3(512), 0, stream,
                     z, Wz, z2h_b, Wo, h2o_b, R.Hlev[5], out);

  R.go(R.Hlev[5], TDEPTH, 0);
}